// Round 11
// baseline (249.651 us; speedup 1.0000x reference)
//
#include <hip/hip_runtime.h>
#include <hip/hip_bf16.h>

#define B_ 4
#define N_ 256
#define D_ 256
#define KG_ 128
#define EPS_ 1e-5f

typedef __bf16 bf16x8 __attribute__((ext_vector_type(8)));
typedef __bf16 bf16x4 __attribute__((ext_vector_type(4)));
typedef float  f32x4v __attribute__((ext_vector_type(4)));

__device__ __forceinline__ void gload16(const void* g, void* l) {
    __builtin_amdgcn_global_load_lds(
        (const __attribute__((address_space(1))) uint32_t*)g,
        (__attribute__((address_space(3))) uint32_t*)l, 16, 0, 0);
}

// ---------------------------------------------------------------------------
// S1: W_kcT[d][g] = sum_k W_kg[g][k] * Wc[k][d]   (bf16, transposed)
//     bias_tot[d] = sum_k b_kg[k] * Wc[k][d] + b1l[d]
// ---------------------------------------------------------------------------
__global__ __launch_bounds__(256) void s1_kernel(
    const float* __restrict__ Wkg, const float* __restrict__ W1l,
    const float* __restrict__ bkg, const float* __restrict__ b1l,
    __bf16* __restrict__ WkcT, float* __restrict__ biastot)
{
    const int d = threadIdx.x;
    if (blockIdx.x == KG_) {
        float acc = 0.f;
        for (int k = 0; k < D_; ++k)
            acc += bkg[k] * W1l[(2 * D_ + k) * D_ + d];
        biastot[d] = acc + b1l[d];
        return;
    }
    const int g = blockIdx.x;
    float acc = 0.f;
    for (int k = 0; k < D_; ++k)
        acc += Wkg[g * D_ + k] * W1l[(2 * D_ + k) * D_ + d];
    WkcT[d * KG_ + g] = (__bf16)acc;
}

// ---------------------------------------------------------------------------
// S2: a_pb[row][d] = (h @ Wa)[row][d] + bias_tot[d]   (fp32)
//     bb  [row][d] = (h @ Wb)[row][d]                  (bf16)
// ---------------------------------------------------------------------------
__global__ __launch_bounds__(256) void s2_kernel(
    const float* __restrict__ hin, const float* __restrict__ W1l,
    const float* __restrict__ biastot,
    float* __restrict__ apb, __bf16* __restrict__ bbout)
{
    __shared__ float hT[D_][4];
    const int tid = threadIdx.x;
    const int R = blockIdx.x * 4;
    {
        const int r = tid & 3, c4 = (tid >> 2) << 2;
        const float4 v = *(const float4*)(hin + (R + r) * D_ + c4);
        hT[c4 + 0][r] = v.x; hT[c4 + 1][r] = v.y;
        hT[c4 + 2][r] = v.z; hT[c4 + 3][r] = v.w;
    }
    __syncthreads();
    float aa[4] = {0.f, 0.f, 0.f, 0.f};
    float ab[4] = {0.f, 0.f, 0.f, 0.f};
#pragma unroll 4
    for (int e = 0; e < D_; ++e) {
        const float wa = W1l[e * D_ + tid];
        const float wb = W1l[(D_ + e) * D_ + tid];
        const float4 hv = *(const float4*)&hT[e][0];
        aa[0] += hv.x * wa; aa[1] += hv.y * wa; aa[2] += hv.z * wa; aa[3] += hv.w * wa;
        ab[0] += hv.x * wb; ab[1] += hv.y * wb; ab[2] += hv.z * wb; ab[3] += hv.w * wb;
    }
    const float bt = biastot[tid];
#pragma unroll
    for (int r = 0; r < 4; ++r) {
        apb[(R + r) * D_ + tid]    = aa[r] + bt;
        bbout[(R + r) * D_ + tid]  = (__bf16)ab[r];
    }
}

// ---------------------------------------------------------------------------
// BIG: grid 4096 = (bi, jc): each block one 64-j chunk of one (b,i) row.
// LDS = 16 KB E-slab only -> ~4 blocks/CU for deep memory concurrency.
//   FROMB=0: reg-stage rel f32 -> bf16 Et (XOR-swizzled) + linear relb copy.
//   FROMB=1: gload_lds from relb (XOR source-swizzle).
// bb read DIRECT from L2 in epilogue. Partial r -> rbuf[(bi*4+jc)*D+d].
// MFMA operand-swapped: D[d][j]; lane (l15=j, lg,q = d-quad).
// ---------------------------------------------------------------------------
template<int FROMB>
__global__ __launch_bounds__(256) void big_kernel(
    const float* __restrict__ rel, __bf16* __restrict__ relb,
    const int* __restrict__ adj,
    const __bf16* __restrict__ WkcT, const float* __restrict__ apb,
    const __bf16* __restrict__ bb, float* __restrict__ rbuf)
{
    __shared__ __align__(16) __bf16 Et[64 * KG_];   // 16 KB
    __shared__ float adjL[64];

    const int tid = threadIdx.x;
    const int lane = tid & 63;
    const int w = tid >> 6;
    const int l15 = lane & 15;
    const int lg = lane >> 4;       // 0..3
    const int bij = blockIdx.x;
    const int bi = bij >> 2;        // b*256 + i
    const int jc = bij & 3;
    const int j0 = jc * 64;
    const int dw = w * 64;

    const float*  Ebase  = rel + ((size_t)bi * N_ + j0) * KG_;
    const __bf16* bbBase = bb + (size_t)(bi >> 8) * N_ * D_ + j0 * D_;

    // persistent Wkc fragments (A-operand): row(d)=l15, k=kk*32+lg*8
    bf16x8 wf[4][4];
#pragma unroll
    for (int nb = 0; nb < 4; ++nb)
#pragma unroll
        for (int kk = 0; kk < 4; ++kk)
            wf[nb][kk] = *(const bf16x8*)(WkcT + (dw + nb * 16 + l15) * KG_ + kk * 32 + lg * 8);

    f32x4v apbv[4];   // d = dw + nb*16 + lg*4 + q
#pragma unroll
    for (int nb = 0; nb < 4; ++nb)
        apbv[nb] = *(const f32x4v*)(apb + bi * D_ + dw + nb * 16 + lg * 4);

    if (tid < 64) adjL[tid] = (float)adj[bi * N_ + j0 + tid];

    // ---- stage Et: 1024 16B-units (64 rows x 16 units) ----
    if (FROMB) {
        const char* Gb = (const char*)(relb + ((size_t)bi * N_ + j0) * KG_);
        char* ldsw = (char*)Et + (tid & 192) * 16;
#pragma unroll
        for (int i = 0; i < 4; ++i) {
            const int u = tid + i * 256;
            const int gu = (u & ~15) | ((u & 15) ^ ((u >> 4) & 7));
            gload16(Gb + gu * 16, ldsw + i * 4096);
        }
    } else {
        __bf16* relbW = relb ? relb + ((size_t)bi * N_ + j0) * KG_ : nullptr;
#pragma unroll
        for (int rep = 0; rep < 4; ++rep) {
            const int v = tid + rep * 256;
            const int row = v >> 4;
            const int k0 = (v & 15) * 8;
            const float* s = Ebase + row * KG_ + k0;
            const f32x4v fa = *(const f32x4v*)s;
            const f32x4v fb = *(const f32x4v*)(s + 4);
            bf16x8 v8;
            v8[0] = (__bf16)fa[0]; v8[1] = (__bf16)fa[1];
            v8[2] = (__bf16)fa[2]; v8[3] = (__bf16)fa[3];
            v8[4] = (__bf16)fb[0]; v8[5] = (__bf16)fb[1];
            v8[6] = (__bf16)fb[2]; v8[7] = (__bf16)fb[3];
            const int off = (row * 256 + k0 * 2) ^ ((row & 7) << 4);
            *(bf16x8*)((char*)Et + off) = v8;
            if (relbW) *(bf16x8*)(relbW + v * 8) = v8;   // linear bf16 copy
        }
    }
    __syncthreads();

    float racc[4][4] = {};

    // ---- compute: 4 jj sub-tiles of 16 j each ----
#pragma unroll
    for (int jj = 0; jj < 4; ++jj) {
        const int row = jj * 16 + l15;
        bf16x8 af[4];
#pragma unroll
        for (int kk = 0; kk < 4; ++kk) {
            const int off = (row * 256 + kk * 64 + lg * 16) ^ ((row & 7) << 4);
            af[kk] = *(const bf16x8*)((const char*)Et + off);
        }
        f32x4v acc[4];
#pragma unroll
        for (int nb = 0; nb < 4; ++nb) acc[nb] = (f32x4v){0.f, 0.f, 0.f, 0.f};
#pragma unroll
        for (int kk = 0; kk < 4; ++kk)
#pragma unroll
            for (int nb = 0; nb < 4; ++nb)
                acc[nb] = __builtin_amdgcn_mfma_f32_16x16x32_bf16(wf[nb][kk], af[kk], acc[nb], 0, 0, 0);

        const float adjj = adjL[row];
        const __bf16* brow = bbBase + row * D_ + dw + lg * 4;   // L2-hot
#pragma unroll
        for (int nb = 0; nb < 4; ++nb) {
            const bf16x4 bv = *(const bf16x4*)(brow + nb * 16);
#pragma unroll
            for (int q = 0; q < 4; ++q) {
                float t = acc[nb][q] + apbv[nb][q] + (float)bv[q];
                t = fmaxf(t, 0.f);
                racc[nb][q] += t * adjj;
            }
        }
    }

    // ---- reduce racc over the 16 l15-lanes (j) -> partial r, write rbuf ----
    float* rout = rbuf + (size_t)bij * D_;
#pragma unroll
    for (int nb = 0; nb < 4; ++nb) {
        float v0 = racc[nb][0], v1 = racc[nb][1], v2 = racc[nb][2], v3 = racc[nb][3];
#pragma unroll
        for (int off = 1; off <= 8; off <<= 1) {
            v0 += __shfl_xor(v0, off, 64);
            v1 += __shfl_xor(v1, off, 64);
            v2 += __shfl_xor(v2, off, 64);
            v3 += __shfl_xor(v3, off, 64);
        }
        if (l15 == 0) {
            float4 o; o.x = v0; o.y = v1; o.z = v2; o.w = v3;
            *(float4*)(rout + dw + nb * 16 + lg * 4) = o;
        }
    }
}

// ---------------------------------------------------------------------------
// TAIL: per (b,i): r = sum of 4 partials; deg = sum(adj); msg = r@W2 + deg*b2;
//       h_out = LN(h_in + msg)*gamma + beta.
// ---------------------------------------------------------------------------
__global__ __launch_bounds__(256) void tail_kernel(
    const float* __restrict__ rbuf, const int* __restrict__ adj,
    const float* __restrict__ W2l, const float* __restrict__ b2l,
    const float* __restrict__ hin, const float* __restrict__ gmm,
    const float* __restrict__ bta, float* __restrict__ hout)
{
    __shared__ float rL[D_];
    __shared__ float red[8];
    __shared__ float dred[4];

    const int tid = threadIdx.x;
    const int lane = tid & 63;
    const int w = tid >> 6;
    const int bi = blockIdx.x;

    const float* rp = rbuf + (size_t)bi * 4 * D_;
    rL[tid] = rp[tid] + rp[D_ + tid] + rp[2 * D_ + tid] + rp[3 * D_ + tid];

    float a = (float)adj[bi * N_ + tid];
#pragma unroll
    for (int off = 32; off >= 1; off >>= 1) a += __shfl_xor(a, off, 64);
    if (lane == 0) dred[w] = a;
    __syncthreads();
    const float sdeg = dred[0] + dred[1] + dred[2] + dred[3];

    const int d = tid;
    float m0 = 0.f, m1 = 0.f, m2 = 0.f, m3 = 0.f;
#pragma unroll 8
    for (int e = 0; e < D_; e += 4) {
        const float4 rv = *(const float4*)&rL[e];
        m0 += rv.x * W2l[(e + 0) * D_ + d];
        m1 += rv.y * W2l[(e + 1) * D_ + d];
        m2 += rv.z * W2l[(e + 2) * D_ + d];
        m3 += rv.w * W2l[(e + 3) * D_ + d];
    }
    const float t = hin[bi * D_ + d] + (m0 + m1) + (m2 + m3) + sdeg * b2l[d];

    float s = t, sq = t * t;
#pragma unroll
    for (int off = 32; off >= 1; off >>= 1) {
        s  += __shfl_xor(s, off, 64);
        sq += __shfl_xor(sq, off, 64);
    }
    if (lane == 0) { red[w] = s; red[4 + w] = sq; }
    __syncthreads();
    const float S  = red[0] + red[1] + red[2] + red[3];
    const float SQ = red[4] + red[5] + red[6] + red[7];
    const float mu = S * (1.f / D_);
    const float var = SQ * (1.f / D_) - mu * mu;
    const float rstd = rsqrtf(var + EPS_);
    hout[bi * D_ + d] = (t - mu) * rstd * gmm[d] + bta[d];
}

// ---------------------------------------------------------------------------
extern "C" void kernel_launch(void* const* d_in, const int* in_sizes, int n_in,
                              void* d_out, int out_size, void* d_ws, size_t ws_size,
                              hipStream_t stream)
{
    const float* node  = (const float*)d_in[0];
    const float* rel   = (const float*)d_in[1];
    const int*   adj   = (const int*)d_in[2];
    const float* Wkg   = (const float*)d_in[3];
    const float* bkg   = (const float*)d_in[4];
    const float* W1    = (const float*)d_in[5];
    const float* b1    = (const float*)d_in[6];
    const float* W2    = (const float*)d_in[7];
    const float* b2    = (const float*)d_in[8];
    const float* gamma = (const float*)d_in[9];
    const float* beta  = (const float*)d_in[10];
    float* out = (float*)d_out;

    char* ws = (char*)d_ws;
    float*  h1    = (float*)(ws);                       // 1 MB
    float*  apb   = (float*)(ws + (1 << 20));           // 1 MB
    __bf16* bbuf  = (__bf16*)(ws + (2 << 20));          // 512 KB
    float*  bias  = (float*)(ws + (3 << 20));           // 1 KB
    __bf16* WkcT  = (__bf16*)(ws + (3 << 20) + 4096);   // 64 KB
    float*  rbuf  = (float*)(ws + (4 << 20));           // 4 MB
    __bf16* relb  = (__bf16*)(ws + (8 << 20));          // 64 MB (if it fits)

    const size_t relElems = (size_t)B_ * N_ * N_ * KG_;           // 33.5 M
    const bool useBF = ws_size >= ((size_t)(8 << 20) + relElems * 2);
    __bf16* relbArg = useBF ? relb : nullptr;

    for (int l = 0; l < 2; ++l) {
        const float* W1l = W1 + (size_t)l * 3 * D_ * D_;
        const float* hin = (l == 0) ? node : h1;
        float* hout = (l == 1) ? out : h1;

        s1_kernel<<<KG_ + 1, 256, 0, stream>>>(Wkg, W1l, bkg, b1 + l * D_, WkcT, bias);
        s2_kernel<<<(B_ * N_) / 4, 256, 0, stream>>>(hin, W1l, bias, apb, bbuf);
        if (l == 0 || !useBF)
            big_kernel<0><<<B_ * N_ * 4, 256, 0, stream>>>(rel, relbArg, adj, WkcT, apb, bbuf, rbuf);
        else
            big_kernel<1><<<B_ * N_ * 4, 256, 0, stream>>>(rel, relbArg, adj, WkcT, apb, bbuf, rbuf);
        tail_kernel<<<B_ * N_, 256, 0, stream>>>(rbuf, adj, W2 + (size_t)l * D_ * D_,
                                                 b2 + l * D_, hin, gamma, beta, hout);
    }
}

// Round 12
// 183.543 us; speedup vs baseline: 1.3602x; 1.3602x over previous
//
#include <hip/hip_runtime.h>
#include <hip/hip_bf16.h>

#define B_ 4
#define N_ 256
#define D_ 256
#define KG_ 128
#define EPS_ 1e-5f

typedef __bf16 bf16x8 __attribute__((ext_vector_type(8)));
typedef __bf16 bf16x4 __attribute__((ext_vector_type(4)));
typedef float  f32x4v __attribute__((ext_vector_type(4)));

__device__ __forceinline__ void gload16(const void* g, void* l) {
    __builtin_amdgcn_global_load_lds(
        (const __attribute__((address_space(1))) uint32_t*)g,
        (__attribute__((address_space(3))) uint32_t*)l, 16, 0, 0);
}

// ---------------------------------------------------------------------------
// S1: W_kcT[d][g] = sum_k W_kg[g][k] * Wc[k][d]   (bf16, transposed)
//     bias_tot[d] = sum_k b_kg[k] * Wc[k][d] + b1l[d]
// ---------------------------------------------------------------------------
__global__ __launch_bounds__(256) void s1_kernel(
    const float* __restrict__ Wkg, const float* __restrict__ W1l,
    const float* __restrict__ bkg, const float* __restrict__ b1l,
    __bf16* __restrict__ WkcT, float* __restrict__ biastot)
{
    const int d = threadIdx.x;
    if (blockIdx.x == KG_) {
        float acc = 0.f;
        for (int k = 0; k < D_; ++k)
            acc += bkg[k] * W1l[(2 * D_ + k) * D_ + d];
        biastot[d] = acc + b1l[d];
        return;
    }
    const int g = blockIdx.x;
    float acc = 0.f;
    for (int k = 0; k < D_; ++k)
        acc += Wkg[g * D_ + k] * W1l[(2 * D_ + k) * D_ + d];
    WkcT[d * KG_ + g] = (__bf16)acc;
}

// ---------------------------------------------------------------------------
// S2: a_pb[row][d] = (h @ Wa)[row][d] + bias_tot[d]   (fp32)
//     bb  [row][d] = (h @ Wb)[row][d]                  (bf16)
// ---------------------------------------------------------------------------
__global__ __launch_bounds__(256) void s2_kernel(
    const float* __restrict__ hin, const float* __restrict__ W1l,
    const float* __restrict__ biastot,
    float* __restrict__ apb, __bf16* __restrict__ bbout)
{
    __shared__ float hT[D_][4];
    const int tid = threadIdx.x;
    const int R = blockIdx.x * 4;
    {
        const int r = tid & 3, c4 = (tid >> 2) << 2;
        const float4 v = *(const float4*)(hin + (R + r) * D_ + c4);
        hT[c4 + 0][r] = v.x; hT[c4 + 1][r] = v.y;
        hT[c4 + 2][r] = v.z; hT[c4 + 3][r] = v.w;
    }
    __syncthreads();
    float aa[4] = {0.f, 0.f, 0.f, 0.f};
    float ab[4] = {0.f, 0.f, 0.f, 0.f};
#pragma unroll 4
    for (int e = 0; e < D_; ++e) {
        const float wa = W1l[e * D_ + tid];
        const float wb = W1l[(D_ + e) * D_ + tid];
        const float4 hv = *(const float4*)&hT[e][0];
        aa[0] += hv.x * wa; aa[1] += hv.y * wa; aa[2] += hv.z * wa; aa[3] += hv.w * wa;
        ab[0] += hv.x * wb; ab[1] += hv.y * wb; ab[2] += hv.z * wb; ab[3] += hv.w * wb;
    }
    const float bt = biastot[tid];
#pragma unroll
    for (int r = 0; r < 4; ++r) {
        apb[(R + r) * D_ + tid]    = aa[r] + bt;
        bbout[(R + r) * D_ + tid]  = (__bf16)ab[r];
    }
}

// ---------------------------------------------------------------------------
// BIG: grid 4096 = (bi, jc); 512 threads = 8 waves; wave w owns 32 d.
// Slim registers (wf[2][4]=32) -> 4 waves/SIMD -> ~16 waves/CU.
// One burst stages BOTH slabs (Et 16 KB reg-cvt, Bt 32 KB gload_lds),
// ONE barrier, all-LDS compute, partial r -> rbuf[(bi*4+jc)*D].
// MFMA operand-swapped: D[d][j]; lane (l15=j, lg,q = d-quad).
// ---------------------------------------------------------------------------
__global__ __launch_bounds__(512, 4) void big_kernel(
    const float* __restrict__ rel, const int* __restrict__ adj,
    const __bf16* __restrict__ WkcT, const float* __restrict__ apb,
    const __bf16* __restrict__ bb, float* __restrict__ rbuf)
{
    __shared__ __align__(16) __bf16 Et[64 * KG_];   // 16 KB
    __shared__ __align__(16) __bf16 Bt[64 * D_];    // 32 KB
    __shared__ float adjL[64];

    const int tid = threadIdx.x;
    const int lane = tid & 63;
    const int w = tid >> 6;         // 0..7
    const int l15 = lane & 15;
    const int lg = lane >> 4;       // 0..3
    const int bij = blockIdx.x;
    const int bi = bij >> 2;        // b*256 + i
    const int jc = bij & 3;
    const int j0 = jc * 64;
    const int dw = w * 32;

    const float*  Ebase  = rel + ((size_t)bi * N_ + j0) * KG_;
    const __bf16* bbBase = bb + (size_t)(bi >> 8) * N_ * D_ + (size_t)j0 * D_;

    // slim Wkc fragments (A-operand): nb<2, row(d)=dw+nb*16+l15, k=kk*32+lg*8
    bf16x8 wf[2][4];
#pragma unroll
    for (int nb = 0; nb < 2; ++nb)
#pragma unroll
        for (int kk = 0; kk < 4; ++kk)
            wf[nb][kk] = *(const bf16x8*)(WkcT + (dw + nb * 16 + l15) * KG_ + kk * 32 + lg * 8);

    f32x4v apbv[2];   // d = dw + nb*16 + lg*4 + q
#pragma unroll
    for (int nb = 0; nb < 2; ++nb)
        apbv[nb] = *(const f32x4v*)(apb + bi * D_ + dw + nb * 16 + lg * 4);

    if (tid < 64) adjL[tid] = (float)adj[bi * N_ + j0 + tid];

    // ---- stage burst ----
    // Bt: 2048 16B-units; LDS unit u <- global unit (u&~31)|((u&31)^((u>>5)&7))
    {
        const char* Gb = (const char*)bbBase;
        char* ldsw = (char*)Bt + (tid & 448) * 16;   // wave-uniform base
#pragma unroll
        for (int i = 0; i < 4; ++i) {
            const int u = tid + i * 512;
            const int gu = (u & ~31) | ((u & 31) ^ ((u >> 5) & 7));
            gload16(Gb + gu * 16, ldsw + i * 8192);
        }
    }
    // Et: 1024 bf16x8-units, reg-cvt from f32, XOR-swizzled rows
    {
#pragma unroll
        for (int rep = 0; rep < 2; ++rep) {
            const int v = tid + rep * 512;
            const int row = v >> 4;
            const int k0 = (v & 15) * 8;
            const float* s = Ebase + row * KG_ + k0;
            const f32x4v fa = *(const f32x4v*)s;
            const f32x4v fb = *(const f32x4v*)(s + 4);
            bf16x8 v8;
            v8[0] = (__bf16)fa[0]; v8[1] = (__bf16)fa[1];
            v8[2] = (__bf16)fa[2]; v8[3] = (__bf16)fa[3];
            v8[4] = (__bf16)fb[0]; v8[5] = (__bf16)fb[1];
            v8[6] = (__bf16)fb[2]; v8[7] = (__bf16)fb[3];
            const int off = (row * 256 + k0 * 2) ^ ((row & 7) << 4);
            *(bf16x8*)((char*)Et + off) = v8;
        }
    }
    __syncthreads();   // the only barrier (drains vmcnt for gload_lds too)

    float racc[2][4] = {};

    // ---- compute: 4 jj sub-tiles of 16 j, all operands LDS/reg ----
#pragma unroll
    for (int jj = 0; jj < 4; ++jj) {
        const int row = jj * 16 + l15;
        bf16x8 af[4];
#pragma unroll
        for (int kk = 0; kk < 4; ++kk) {
            const int off = (row * 256 + kk * 64 + lg * 16) ^ ((row & 7) << 4);
            af[kk] = *(const bf16x8*)((const char*)Et + off);
        }
        f32x4v acc[2];
#pragma unroll
        for (int nb = 0; nb < 2; ++nb) acc[nb] = (f32x4v){0.f, 0.f, 0.f, 0.f};
#pragma unroll
        for (int kk = 0; kk < 4; ++kk)
#pragma unroll
            for (int nb = 0; nb < 2; ++nb)
                acc[nb] = __builtin_amdgcn_mfma_f32_16x16x32_bf16(wf[nb][kk], af[kk], acc[nb], 0, 0, 0);

        const float adjj = adjL[row];
#pragma unroll
        for (int nb = 0; nb < 2; ++nb) {
            const int dbyte = w * 64 + nb * 32 + lg * 8;           // d*2
            const int su = (dbyte >> 4) ^ (row & 7);
            const bf16x4 bv = *(const bf16x4*)((const char*)Bt + row * 512 + su * 16 + (dbyte & 15));
#pragma unroll
            for (int q = 0; q < 4; ++q) {
                float t = acc[nb][q] + apbv[nb][q] + (float)bv[q];
                t = fmaxf(t, 0.f);
                racc[nb][q] += t * adjj;
            }
        }
    }

    // ---- reduce racc over the 16 l15-lanes (j) -> partial r ----
    float* rout = rbuf + (size_t)bij * D_;
#pragma unroll
    for (int nb = 0; nb < 2; ++nb) {
        float v0 = racc[nb][0], v1 = racc[nb][1], v2 = racc[nb][2], v3 = racc[nb][3];
#pragma unroll
        for (int off = 1; off <= 8; off <<= 1) {
            v0 += __shfl_xor(v0, off, 64);
            v1 += __shfl_xor(v1, off, 64);
            v2 += __shfl_xor(v2, off, 64);
            v3 += __shfl_xor(v3, off, 64);
        }
        if (l15 == 0) {
            float4 o; o.x = v0; o.y = v1; o.z = v2; o.w = v3;
            *(float4*)(rout + dw + nb * 16 + lg * 4) = o;
        }
    }
}

// ---------------------------------------------------------------------------
// TAIL: per (b,i): r = sum of 4 partials; deg = sum(adj); msg = r@W2 + deg*b2;
//       h_out = LN(h_in + msg)*gamma + beta.
// ---------------------------------------------------------------------------
__global__ __launch_bounds__(256) void tail_kernel(
    const float* __restrict__ rbuf, const int* __restrict__ adj,
    const float* __restrict__ W2l, const float* __restrict__ b2l,
    const float* __restrict__ hin, const float* __restrict__ gmm,
    const float* __restrict__ bta, float* __restrict__ hout)
{
    __shared__ float rL[D_];
    __shared__ float red[8];
    __shared__ float dred[4];

    const int tid = threadIdx.x;
    const int lane = tid & 63;
    const int w = tid >> 6;
    const int bi = blockIdx.x;

    const float* rp = rbuf + (size_t)bi * 4 * D_;
    rL[tid] = rp[tid] + rp[D_ + tid] + rp[2 * D_ + tid] + rp[3 * D_ + tid];

    float a = (float)adj[bi * N_ + tid];
#pragma unroll
    for (int off = 32; off >= 1; off >>= 1) a += __shfl_xor(a, off, 64);
    if (lane == 0) dred[w] = a;
    __syncthreads();
    const float sdeg = dred[0] + dred[1] + dred[2] + dred[3];

    const int d = tid;
    float m0 = 0.f, m1 = 0.f, m2 = 0.f, m3 = 0.f;
#pragma unroll 8
    for (int e = 0; e < D_; e += 4) {
        const float4 rv = *(const float4*)&rL[e];
        m0 += rv.x * W2l[(e + 0) * D_ + d];
        m1 += rv.y * W2l[(e + 1) * D_ + d];
        m2 += rv.z * W2l[(e + 2) * D_ + d];
        m3 += rv.w * W2l[(e + 3) * D_ + d];
    }
    const float t = hin[bi * D_ + d] + (m0 + m1) + (m2 + m3) + sdeg * b2l[d];

    float s = t, sq = t * t;
#pragma unroll
    for (int off = 32; off >= 1; off >>= 1) {
        s  += __shfl_xor(s, off, 64);
        sq += __shfl_xor(sq, off, 64);
    }
    if (lane == 0) { red[w] = s; red[4 + w] = sq; }
    __syncthreads();
    const float S  = red[0] + red[1] + red[2] + red[3];
    const float SQ = red[4] + red[5] + red[6] + red[7];
    const float mu = S * (1.f / D_);
    const float var = SQ * (1.f / D_) - mu * mu;
    const float rstd = rsqrtf(var + EPS_);
    hout[bi * D_ + d] = (t - mu) * rstd * gmm[d] + bta[d];
}

// ---------------------------------------------------------------------------
extern "C" void kernel_launch(void* const* d_in, const int* in_sizes, int n_in,
                              void* d_out, int out_size, void* d_ws, size_t ws_size,
                              hipStream_t stream)
{
    const float* node  = (const float*)d_in[0];
    const float* rel   = (const float*)d_in[1];
    const int*   adj   = (const int*)d_in[2];
    const float* Wkg   = (const float*)d_in[3];
    const float* bkg   = (const float*)d_in[4];
    const float* W1    = (const float*)d_in[5];
    const float* b1    = (const float*)d_in[6];
    const float* W2    = (const float*)d_in[7];
    const float* b2    = (const float*)d_in[8];
    const float* gamma = (const float*)d_in[9];
    const float* beta  = (const float*)d_in[10];
    float* out = (float*)d_out;

    char* ws = (char*)d_ws;
    float*  h1    = (float*)(ws);                       // 1 MB
    float*  apb   = (float*)(ws + (1 << 20));           // 1 MB
    __bf16* bbuf  = (__bf16*)(ws + (2 << 20));          // 512 KB
    float*  bias  = (float*)(ws + (3 << 20));           // 1 KB
    __bf16* WkcT  = (__bf16*)(ws + (3 << 20) + 4096);   // 64 KB
    float*  rbuf  = (float*)(ws + (4 << 20));           // 4 MB

    for (int l = 0; l < 2; ++l) {
        const float* W1l = W1 + (size_t)l * 3 * D_ * D_;
        const float* hin = (l == 0) ? node : h1;
        float* hout = (l == 1) ? out : h1;

        s1_kernel<<<KG_ + 1, 256, 0, stream>>>(Wkg, W1l, bkg, b1 + l * D_, WkcT, bias);
        s2_kernel<<<(B_ * N_) / 4, 256, 0, stream>>>(hin, W1l, bias, apb, bbuf);
        big_kernel<<<B_ * N_ * 4, 512, 0, stream>>>(rel, adj, WkcT, apb, bbuf, rbuf);
        tail_kernel<<<B_ * N_, 256, 0, stream>>>(rbuf, adj, W2 + (size_t)l * D_ * D_,
                                                 b2 + l * D_, hin, gamma, beta, hout);
    }
}